// Round 1
// baseline (51.309 us; speedup 1.0000x reference)
//
#include <hip/hip_runtime.h>
#include <hip/hip_bf16.h>

#define NF 262144   // C*H*W
#define NROWS 32    // batch

typedef __attribute__((ext_vector_type(8))) __bf16 bf16x8;
typedef __attribute__((ext_vector_type(16))) float f32x16;

__device__ __forceinline__ float sigmoid_fast(float x) {
    // 1/(1+exp(-x)); v_exp-based fast exp + v_rcp (plenty accurate for 2% threshold)
    float e = __expf(-x);
    return __builtin_amdgcn_rcpf(1.0f + e);
}

// ws layout (floats): [0,1024) cross[32][32]; [1024,1056) pos; [1056,1088) sq1; [1088,1120) sq2
__global__ __launch_bounds__(256) void cl_main(const float* __restrict__ in1,
                                               const float* __restrict__ in2,
                                               const float* __restrict__ msk,
                                               float* __restrict__ ws) {
    const int tid  = threadIdx.x;
    const int wid  = tid >> 6;
    const int lane = tid & 63;
    const int r    = lane & 31;   // batch row this lane owns (MFMA A/B frag row)
    const int g    = lane >> 5;   // k-group (0/1) within 16-col MFMA step
    const int gw   = blockIdx.x * 4 + wid;           // global wave id, [0,2048)
    const size_t rowoff = (size_t)r * NF;
    const int cbase = gw * 128 + g * 8;              // this wave spans 128 cols

    f32x16 acc;
    #pragma unroll
    for (int k = 0; k < 16; ++k) acc[k] = 0.0f;
    float pos = 0.0f, q1 = 0.0f, q2 = 0.0f;

    #pragma unroll 2
    for (int s = 0; s < 8; ++s) {
        const int c0 = cbase + s * 16;
        float xa[8], xb[8], xm[8];
        const float4* p1 = reinterpret_cast<const float4*>(in1 + rowoff + c0);
        const float4* p2 = reinterpret_cast<const float4*>(in2 + rowoff + c0);
        const float4* pm = reinterpret_cast<const float4*>(msk + rowoff + c0);
        *reinterpret_cast<float4*>(&xa[0]) = p1[0];
        *reinterpret_cast<float4*>(&xa[4]) = p1[1];
        *reinterpret_cast<float4*>(&xb[0]) = p2[0];
        *reinterpret_cast<float4*>(&xb[4]) = p2[1];
        *reinterpret_cast<float4*>(&xm[0]) = pm[0];
        *reinterpret_cast<float4*>(&xm[4]) = pm[1];

        bf16x8 fa, fb;
        #pragma unroll
        for (int e = 0; e < 8; ++e) {
            float sa = sigmoid_fast(xa[e]);
            float sb = sigmoid_fast(xb[e]);
            float t = xm[e] * (sa - sb);
            pos = fmaf(t, t, pos);
            q1  = fmaf(sa, sa, q1);
            q2  = fmaf(sb, sb, q2);
            fa[e] = (__bf16)sa;
            fb[e] = (__bf16)sb;
        }
        // cross[i][j] += sum_k x1[i][k] * x2[j][k]   (A = x1 MxK, B = x2^T KxN)
        acc = __builtin_amdgcn_mfma_f32_32x32x16_bf16(fa, fb, acc, 0, 0, 0);
    }

    // ---- block reduction ----
    __shared__ float s_cross[32][32];
    __shared__ float s_vec[3][32];
    for (int idx = tid; idx < 1024; idx += 256) (&s_cross[0][0])[idx] = 0.0f;
    if (tid < 96) (&s_vec[0][0])[tid] = 0.0f;
    __syncthreads();

    pos += __shfl_down(pos, 32);
    q1  += __shfl_down(q1, 32);
    q2  += __shfl_down(q2, 32);
    if (lane < 32) {
        atomicAdd(&s_vec[0][r], pos);
        atomicAdd(&s_vec[1][r], q1);
        atomicAdd(&s_vec[2][r], q2);
    }
    const int col = lane & 31;
    const int rhi = (lane >> 5) * 4;
    #pragma unroll
    for (int reg = 0; reg < 16; ++reg) {
        const int row = (reg & 3) + 8 * (reg >> 2) + rhi;  // verified C/D mapping
        atomicAdd(&s_cross[row][col], acc[reg]);
    }
    __syncthreads();

    for (int idx = tid; idx < 1024; idx += 256) atomicAdd(&ws[idx], (&s_cross[0][0])[idx]);
    if (tid < 96) atomicAdd(&ws[1024 + tid], (&s_vec[0][0])[tid]);
}

__global__ __launch_bounds__(1024) void cl_final(const float* __restrict__ ws,
                                                 float* __restrict__ out) {
    __shared__ float s_loss[32];
    const int tid = threadIdx.x;
    const int i = tid >> 5, j = tid & 31;
    const float invN = 1.0f / (float)NF;

    float c  = ws[i * 32 + j];
    float p  = ws[1024 + i];
    float s1 = ws[1056 + i];
    float s2 = ws[1088 + j];

    float d = (s1 + s2 - 2.0f * c) * invN;
    float sim = (i == j) ? 0.0f : expf(-d * 10.0f);   // TAU = 0.1
    #pragma unroll
    for (int off = 16; off; off >>= 1) sim += __shfl_xor(sim, off);

    if (j == 0) {
        float sp = expf(-p * invN * 10.0f);
        s_loss[i] = -logf(sp / (sp + sim));
    }
    __syncthreads();
    if (tid == 0) {
        float t = 0.0f;
        #pragma unroll
        for (int k = 0; k < 32; ++k) t += s_loss[k];
        out[0] = t * (1.0f / 32.0f);
    }
}

extern "C" void kernel_launch(void* const* d_in, const int* in_sizes, int n_in,
                              void* d_out, int out_size, void* d_ws, size_t ws_size,
                              hipStream_t stream) {
    const float* in1 = (const float*)d_in[0];
    const float* in2 = (const float*)d_in[1];
    const float* msk = (const float*)d_in[2];
    float* out = (float*)d_out;
    float* ws  = (float*)d_ws;

    hipMemsetAsync(ws, 0, 1120 * sizeof(float), stream);
    cl_main<<<512, 256, 0, stream>>>(in1, in2, msk, ws);
    cl_final<<<1, 1024, 0, stream>>>(ws, out);
}